// Round 4
// baseline (301.721 us; speedup 1.0000x reference)
//
#include <hip/hip_runtime.h>

#define ERRV 1e-6f
#define EPSV 1e-12f
#define THRV 1e-10f
#define MAXV 128

struct F3 { float x, y, z; };

__device__ __forceinline__ F3 mk3(float x, float y, float z){ F3 r; r.x=x; r.y=y; r.z=z; return r; }
__device__ __forceinline__ F3 cross3(F3 a, F3 b){
  return mk3(a.y*b.z - a.z*b.y, a.z*b.x - a.x*b.z, a.x*b.y - a.y*b.x);
}
__device__ __forceinline__ float dot3(F3 a, F3 b){ return a.x*b.x + a.y*b.y + a.z*b.z; }
__device__ __forceinline__ F3 norm3(F3 a){
  float n = sqrtf(dot3(a,a));
  float d = fmaxf(n, EPSV);
  return mk3(a.x/d, a.y/d, a.z/d);
}
// Hamilton product r = a (x) b : apply b's rotation first, then a's.
__device__ __forceinline__ float4 qmul(float4 a, float4 b){
  float4 r;
  r.w = a.w*b.w - (a.x*b.x + a.y*b.y + a.z*b.z);
  r.x = a.w*b.x + b.w*a.x + (a.y*b.z - a.z*b.y);
  r.y = a.w*b.y + b.w*a.y + (a.z*b.x - a.x*b.z);
  r.z = a.w*b.z + b.w*a.z + (a.x*b.y - a.y*b.x);
  return r;
}
// rotate x by unit quaternion q: t = 2 v x X ; x' = x + w t + v x t  (== reference's step)
__device__ __forceinline__ F3 qrot(float4 q, F3 x){
  F3 v = mk3(q.x, q.y, q.z);
  F3 t = cross3(v, x);
  t = mk3(2.f*t.x, 2.f*t.y, 2.f*t.z);
  F3 ct = cross3(v, t);
  return mk3(x.x + q.w*t.x + ct.x, x.y + q.w*t.y + ct.y, x.z + q.w*t.z + ct.z);
}

extern "C" __global__ void __launch_bounds__(MAXV)
rod_energy_kernel(const float* __restrict__ verts,      // B,V,3
                  const float* __restrict__ initd,      // B,3
                  const float* __restrict__ restEdgeL,  // B,E
                  const float* __restrict__ restRegionL,// B,E
                  const float* __restrict__ Wprev,      // B,E,2
                  const float* __restrict__ Wnext,      // B,E,2
                  const float* __restrict__ theta,      // B,E
                  const float* __restrict__ bend,       // 1,E (bcast) or B,E
                  const float* __restrict__ twist,      // 1,E (bcast) or B,E
                  float* __restrict__ out_m1,
                  float* __restrict__ out_m2,
                  float* __restrict__ out_kb,
                  float* __restrict__ out_en,
                  int V, int E, long long bendStride, long long twistStride)
{
  __shared__ float  sV[MAXV*3];   // raw vertex row (V*3 floats)
  __shared__ float4 sQ[MAXV];
  __shared__ int    sJ[MAXV];
  __shared__ float  sR[MAXV];

  const int b = blockIdx.x;
  const int e = threadIdx.x;              // edge index (thread V-1 inactive for most work)
  const bool act = (e < E);

  // ---- stage vertex row into LDS with coalesced float4 loads ----
  // V*3 floats = (V*3)/4 float4 (V=128 -> 96 lanes x 16B = full 1536B row).
  const float* vb = verts + (size_t)b * V * 3;
  {
    const int nv4 = (V * 3) >> 2;
    if (e < nv4) ((float4*)sV)[e] = ((const float4*)vb)[e];
  }
  __syncthreads();

  // edge(i) helper from LDS
  #define EDGE(i) mk3(sV[((i)+1)*3+0]-sV[(i)*3+0], \
                      sV[((i)+1)*3+1]-sV[(i)*3+1], \
                      sV[((i)+1)*3+2]-sV[(i)*3+2])

  F3 edge = act ? EDGE(e) : mk3(0.f,0.f,0.f);

  // ---- kb + per-edge rotation quaternion ----
  const size_t rowE = (size_t)b * E;
  F3 kb = mk3(0.f, 0.f, 0.f);
  float4 q = make_float4(0.f, 0.f, 0.f, 1.f);  // identity
  int j = 0;                                   // last edge index with a real rotation
  if (act && e >= 1) {
    F3 ep = EDGE(e-1);
    float rl  = restEdgeL[rowE + e];
    float rlp = restEdgeL[rowE + e - 1];
    F3 cr = cross3(ep, edge);
    float den = rlp*rl + dot3(ep, edge);
    kb = mk3(2.f*cr.x/den, 2.f*cr.y/den, 2.f*cr.z/den);
    float mag  = dot3(kb, kb);
    float sinP = sqrtf(mag/(mag+4.f));
    float cosP = sqrtf(4.f/(mag+4.f));
    float nrm  = sqrtf(mag);
    float dnm  = fmaxf(nrm, EPSV);
    bool cond = (1.f - cosP) <= ERRV;          // tiny rotation -> identity (matches jnp.where)
    if (!cond) {
      float axx = kb.x/dnm, axy = kb.y/dnm, axz = kb.z/dnm;
      q = make_float4(sinP*axx, sinP*axy, sinP*axz, cosP);
      j = e;
    }
  }

  // ---- Hillis-Steele inclusive scan: M_e = R_e (x) ... (x) R_1 ; jmax ----
  // identity qmul is bitwise-transparent, so "keep previous" steps match the
  // reference's jnp.where semantics exactly.
  sQ[e] = q; sJ[e] = j;
  #pragma unroll
  for (int d = 1; d < MAXV; d <<= 1) {
    __syncthreads();
    float4 qp; int jp;
    const bool has = (e >= d);
    if (has) { qp = sQ[e-d]; jp = sJ[e-d]; }
    __syncthreads();
    if (has) { q = qmul(q, qp); j = (j > jp ? j : jp); sQ[e] = q; sJ[e] = j; }
  }
  __syncthreads();

  // ---- u0, v0 (all threads redundantly; bitwise-identical) ----
  F3 e0  = EDGE(0);
  F3 dir = mk3(initd[(size_t)b*3+0], initd[(size_t)b*3+1], initd[(size_t)b*3+2]);
  F3 n0  = cross3(e0, dir);
  F3 u0  = norm3(cross3(n0, e0));
  F3 v0  = norm3(cross3(e0, u0));

  F3 u = u0, v = v0;
  if (act && e >= 1) {
    u = qrot(q, u0);                 // == u0 bitwise if prefix is all-identity
    if (j > 0) {
      F3 ej = EDGE(j);
      v = norm3(cross3(ej, u));      // u unchanged since step j => matches reference rv
    }
  }

  // ---- material frame ----
  float th = act ? theta[rowE + e] : 0.f;
  float cq, sq;
  sincosf(th, &sq, &cq);             // precise: outputs feed absmax-checked m1/m2
  F3 m1 = mk3(cq*u.x + sq*v.x, cq*u.y + sq*v.y, cq*u.z + sq*v.z);
  F3 m2 = mk3(-sq*m1.x + cq*v.x, -sq*m1.y + cq*v.y, -sq*m1.z + cq*v.z);

  // ---- outputs + energy contribution ----
  float contrib = 0.f;
  if (act) {
    size_t o3 = (rowE + e) * 3;
    out_m1[o3+0] = m1.x; out_m1[o3+1] = m1.y; out_m1[o3+2] = m1.z;
    out_m2[o3+0] = m2.x; out_m2[o3+1] = m2.y; out_m2[o3+2] = m2.z;
    out_kb[o3+0] = kb.x; out_kb[o3+1] = kb.y; out_kb[o3+2] = kb.z;
    if (e >= 1) {
      float rrl = restRegionL[rowE + e];
      float wx =  dot3(kb, m2);
      float wy = -dot3(kb, m1);
      float2 wp = ((const float2*)Wprev)[rowE + e];
      float2 wn = ((const float2*)Wnext)[rowE + e];
      float dpx = wx - wp.x, dpy = wy - wp.y;
      float dnx = wx - wn.x, dny = wy - wn.y;
      float bsl = fmaxf(bend[bendStride*b + (E-1)], THRV);
      float bsn = fmaxf(bend[bendStride*b + e],     THRV);
      contrib = 0.5f*(bsl*(dpx*dpx + dpy*dpy) + bsn*(dnx*dnx + dny*dny)) / rrl;
      float dm = th - theta[rowE + e - 1];
      float ts = fmaxf(twist[twistStride*b + e], THRV);
      contrib += 0.5f*ts*dm*dm / rrl;
    }
  }

  // ---- block reduction for energy ----
  sR[e] = contrib;
  __syncthreads();
  #pragma unroll
  for (int s = MAXV/2; s > 0; s >>= 1) {
    if (e < s) sR[e] += sR[e+s];
    __syncthreads();
  }
  if (e == 0) out_en[b] = sR[0];
  #undef EDGE
}

extern "C" void kernel_launch(void* const* d_in, const int* in_sizes, int n_in,
                              void* d_out, int out_size, void* d_ws, size_t ws_size,
                              hipStream_t stream)
{
  const float* verts       = (const float*)d_in[0];
  const float* initd       = (const float*)d_in[1];
  const float* restEdgeL   = (const float*)d_in[2];
  const float* restRegionL = (const float*)d_in[3];
  const float* Wprev       = (const float*)d_in[4];
  const float* Wnext       = (const float*)d_in[5];
  const float* theta       = (const float*)d_in[6];
  const float* bend        = (const float*)d_in[7];
  const float* twist       = (const float*)d_in[8];

  long long B = in_sizes[1] / 3;
  long long V = (long long)in_sizes[0] / (3*B);
  long long E = V - 1;
  long long bendStride  = ((long long)in_sizes[7] >= B*E) ? E : 0;
  long long twistStride = ((long long)in_sizes[8] >= B*E) ? E : 0;

  float* out_m1 = (float*)d_out;
  float* out_m2 = out_m1 + (size_t)(B*E*3);
  float* out_kb = out_m2 + (size_t)(B*E*3);
  float* out_en = out_kb + (size_t)(B*E*3);

  dim3 grid((unsigned)B), block((unsigned)V);
  hipLaunchKernelGGL(rod_energy_kernel, grid, block, 0, stream,
                     verts, initd, restEdgeL, restRegionL, Wprev, Wnext, theta,
                     bend, twist, out_m1, out_m2, out_kb, out_en,
                     (int)V, (int)E, bendStride, twistStride);
}

// Round 6
// 292.540 us; speedup vs baseline: 1.0314x; 1.0314x over previous
//
#include <hip/hip_runtime.h>

#define ERRV 1e-6f
#define EPSV 1e-12f
#define THRV 1e-10f
#define MAXV 128

struct F3 { float x, y, z; };

__device__ __forceinline__ F3 mk3(float x, float y, float z){ F3 r; r.x=x; r.y=y; r.z=z; return r; }
__device__ __forceinline__ F3 cross3(F3 a, F3 b){
  return mk3(a.y*b.z - a.z*b.y, a.z*b.x - a.x*b.z, a.x*b.y - a.y*b.x);
}
__device__ __forceinline__ float dot3(F3 a, F3 b){ return a.x*b.x + a.y*b.y + a.z*b.z; }
// fast normalize: x * rsq(|x|^2). Guard keeps degenerate vectors -> 0 (matches x/max(n,eps)).
__device__ __forceinline__ F3 norm3f(F3 a){
  float r = __builtin_amdgcn_rsqf(fmaxf(dot3(a,a), 1e-24f));
  return mk3(a.x*r, a.y*r, a.z*r);
}
// Hamilton product r = a (x) b : apply b's rotation first, then a's.
__device__ __forceinline__ float4 qmul(float4 a, float4 b){
  float4 r;
  r.w = a.w*b.w - (a.x*b.x + a.y*b.y + a.z*b.z);
  r.x = a.w*b.x + b.w*a.x + (a.y*b.z - a.z*b.y);
  r.y = a.w*b.y + b.w*a.y + (a.z*b.x - a.x*b.z);
  r.z = a.w*b.z + b.w*a.z + (a.x*b.y - a.y*b.x);
  return r;
}
// rotate x by unit quaternion q: t = 2 v x X ; x' = x + w t + v x t  (== reference's step)
__device__ __forceinline__ F3 qrot(float4 q, F3 x){
  F3 v = mk3(q.x, q.y, q.z);
  F3 t = cross3(v, x);
  t = mk3(2.f*t.x, 2.f*t.y, 2.f*t.z);
  F3 ct = cross3(v, t);
  return mk3(x.x + q.w*t.x + ct.x, x.y + q.w*t.y + ct.y, x.z + q.w*t.z + ct.z);
}

extern "C" __global__ void __launch_bounds__(MAXV)
rod_energy_kernel(const float* __restrict__ verts,      // B,V,3
                  const float* __restrict__ initd,      // B,3
                  const float* __restrict__ restEdgeL,  // B,E
                  const float* __restrict__ restRegionL,// B,E
                  const float* __restrict__ Wprev,      // B,E,2
                  const float* __restrict__ Wnext,      // B,E,2
                  const float* __restrict__ theta,      // B,E
                  const float* __restrict__ bend,       // 1,E (bcast) or B,E
                  const float* __restrict__ twist,      // 1,E (bcast) or B,E
                  float* __restrict__ out_m1,
                  float* __restrict__ out_m2,
                  float* __restrict__ out_kb,
                  float* __restrict__ out_en,
                  int V, int E, long long bendStride, long long twistStride)
{
  __shared__ float  sV[MAXV*3];   // raw vertex row (V*3 floats)
  __shared__ float4 sQ[MAXV];
  __shared__ int    sJ[MAXV];
  __shared__ float  sW[2];

  const int b = blockIdx.x;
  const int e = threadIdx.x;              // edge index (thread V-1 inactive for most work)
  const bool act = (e < E);

  // ---- stage vertex row into LDS with coalesced float4 loads ----
  const float* vb = verts + (size_t)b * V * 3;
  {
    const int nv4 = (V * 3) >> 2;
    if (e < nv4) ((float4*)sV)[e] = ((const float4*)vb)[e];
  }
  __syncthreads();

  #define EDGE(i) mk3(sV[((i)+1)*3+0]-sV[(i)*3+0], \
                      sV[((i)+1)*3+1]-sV[(i)*3+1], \
                      sV[((i)+1)*3+2]-sV[(i)*3+2])

  F3 edge = act ? EDGE(e) : mk3(0.f,0.f,0.f);

  // ---- kb + per-edge rotation quaternion ----
  // kb and cosP keep the reference-exact expressions (they feed the cond bit);
  // q uses the algebraic identity  sinP*axis = kb/sqrt(mag+4), cosP = 2/sqrt(mag+4).
  const size_t rowE = (size_t)b * E;
  F3 kb = mk3(0.f, 0.f, 0.f);
  float4 q = make_float4(0.f, 0.f, 0.f, 1.f);  // identity
  int j = 0;                                   // last edge index with a real rotation
  if (act && e >= 1) {
    F3 ep = EDGE(e-1);
    float rl  = restEdgeL[rowE + e];
    float rlp = restEdgeL[rowE + e - 1];
    F3 cr = cross3(ep, edge);
    float den = rlp*rl + dot3(ep, edge);
    kb = mk3(2.f*cr.x/den, 2.f*cr.y/den, 2.f*cr.z/den);   // exact divs (cond-sensitive)
    float mag  = dot3(kb, kb);
    float cosP = sqrtf(4.f/(mag+4.f));                    // exact (cond-sensitive)
    bool cond = (1.f - cosP) <= ERRV;                     // tiny rotation -> identity
    if (!cond) {
      float r = __builtin_amdgcn_rsqf(mag + 4.f);
      q = make_float4(kb.x*r, kb.y*r, kb.z*r, 2.f*r);     // unit by construction
      j = e;
    }
  }

  // ---- Hillis-Steele inclusive scan: M_e = R_e (x) ... (x) R_1 ; jmax ----
  sQ[e] = q; sJ[e] = j;
  #pragma unroll
  for (int d = 1; d < MAXV; d <<= 1) {
    __syncthreads();
    float4 qp; int jp;
    const bool has = (e >= d);
    if (has) { qp = sQ[e-d]; jp = sJ[e-d]; }
    __syncthreads();
    if (has) { q = qmul(q, qp); j = (j > jp ? j : jp); sQ[e] = q; sJ[e] = j; }
  }
  __syncthreads();

  // ---- u0, v0 (all threads redundantly; wave-uniform so time-free per wave) ----
  F3 e0  = EDGE(0);
  F3 dir = mk3(initd[(size_t)b*3+0], initd[(size_t)b*3+1], initd[(size_t)b*3+2]);
  F3 n0  = cross3(e0, dir);
  F3 u0  = norm3f(cross3(n0, e0));
  F3 v0  = norm3f(cross3(e0, u0));

  F3 u = u0, v = v0;
  if (act && e >= 1) {
    u = qrot(q, u0);                 // == u0 bitwise if prefix is all-identity
    if (j > 0) {
      F3 ej = EDGE(j);
      v = norm3f(cross3(ej, u));     // u unchanged since step j => matches reference rv
    }
  }

  // ---- material frame (hw sin/cos; |theta| small, err ~2^-21) ----
  float th = act ? theta[rowE + e] : 0.f;
  float cq, sq;
  __sincosf(th, &sq, &cq);
  F3 m1 = mk3(cq*u.x + sq*v.x, cq*u.y + sq*v.y, cq*u.z + sq*v.z);
  F3 m2 = mk3(-sq*m1.x + cq*v.x, -sq*m1.y + cq*v.y, -sq*m1.z + cq*v.z);

  // ---- outputs + energy contribution ----
  float contrib = 0.f;
  if (act) {
    size_t o3 = (rowE + e) * 3;
    out_m1[o3+0] = m1.x; out_m1[o3+1] = m1.y; out_m1[o3+2] = m1.z;
    out_m2[o3+0] = m2.x; out_m2[o3+1] = m2.y; out_m2[o3+2] = m2.z;
    out_kb[o3+0] = kb.x; out_kb[o3+1] = kb.y; out_kb[o3+2] = kb.z;
    if (e >= 1) {
      float rrli = __builtin_amdgcn_rcpf(restRegionL[rowE + e]);  // energy: abs-tiny, rcp ok
      float wx =  dot3(kb, m2);
      float wy = -dot3(kb, m1);
      float2 wp = ((const float2*)Wprev)[rowE + e];
      float2 wn = ((const float2*)Wnext)[rowE + e];
      float dpx = wx - wp.x, dpy = wy - wp.y;
      float dnx = wx - wn.x, dny = wy - wn.y;
      float bsl = fmaxf(bend[bendStride*b + (E-1)], THRV);
      float bsn = fmaxf(bend[bendStride*b + e],     THRV);
      contrib = 0.5f*(bsl*(dpx*dpx + dpy*dpy) + bsn*(dnx*dnx + dny*dny)) * rrli;
      float dm = th - theta[rowE + e - 1];
      float ts = fmaxf(twist[twistStride*b + e], THRV);
      contrib += 0.5f*ts*dm*dm * rrli;
    }
  }

  // ---- energy reduction: wave shuffle-reduce, then combine 2 waves ----
  float c = contrib;
  #pragma unroll
  for (int m = 1; m < 64; m <<= 1) c += __shfl_xor(c, m, 64);
  if ((e & 63) == 0) sW[e >> 6] = c;
  __syncthreads();
  if (e == 0) out_en[b] = sW[0] + sW[1];
  #undef EDGE
}

extern "C" void kernel_launch(void* const* d_in, const int* in_sizes, int n_in,
                              void* d_out, int out_size, void* d_ws, size_t ws_size,
                              hipStream_t stream)
{
  const float* verts       = (const float*)d_in[0];
  const float* initd       = (const float*)d_in[1];
  const float* restEdgeL   = (const float*)d_in[2];
  const float* restRegionL = (const float*)d_in[3];
  const float* Wprev       = (const float*)d_in[4];
  const float* Wnext       = (const float*)d_in[5];
  const float* theta       = (const float*)d_in[6];
  const float* bend        = (const float*)d_in[7];
  const float* twist       = (const float*)d_in[8];

  long long B = in_sizes[1] / 3;
  long long V = (long long)in_sizes[0] / (3*B);
  long long E = V - 1;
  long long bendStride  = ((long long)in_sizes[7] >= B*E) ? E : 0;
  long long twistStride = ((long long)in_sizes[8] >= B*E) ? E : 0;

  float* out_m1 = (float*)d_out;
  float* out_m2 = out_m1 + (size_t)(B*E*3);
  float* out_kb = out_m2 + (size_t)(B*E*3);
  float* out_en = out_kb + (size_t)(B*E*3);

  dim3 grid((unsigned)B), block((unsigned)V);
  hipLaunchKernelGGL(rod_energy_kernel, grid, block, 0, stream,
                     verts, initd, restEdgeL, restRegionL, Wprev, Wnext, theta,
                     bend, twist, out_m1, out_m2, out_kb, out_en,
                     (int)V, (int)E, bendStride, twistStride);
}

// Round 8
// 292.475 us; speedup vs baseline: 1.0316x; 1.0002x over previous
//
#include <hip/hip_runtime.h>

#define ERRV 1e-6f
#define THRV 1e-10f

struct F3 { float x, y, z; };

__device__ __forceinline__ F3 mk3(float x, float y, float z){ F3 r; r.x=x; r.y=y; r.z=z; return r; }
__device__ __forceinline__ F3 cross3(F3 a, F3 b){
  return mk3(a.y*b.z - a.z*b.y, a.z*b.x - a.x*b.z, a.x*b.y - a.y*b.x);
}
__device__ __forceinline__ float dot3(F3 a, F3 b){ return a.x*b.x + a.y*b.y + a.z*b.z; }
__device__ __forceinline__ F3 norm3f(F3 a){
  float r = __builtin_amdgcn_rsqf(fmaxf(dot3(a,a), 1e-24f));
  return mk3(a.x*r, a.y*r, a.z*r);
}
// Hamilton product r = a (x) b : apply b first, then a.
__device__ __forceinline__ float4 qmul(float4 a, float4 b){
  float4 r;
  r.w = a.w*b.w - (a.x*b.x + a.y*b.y + a.z*b.z);
  r.x = a.w*b.x + b.w*a.x + (a.y*b.z - a.z*b.y);
  r.y = a.w*b.y + b.w*a.y + (a.z*b.x - a.x*b.z);
  r.z = a.w*b.z + b.w*a.z + (a.x*b.y - a.y*b.x);
  return r;
}
__device__ __forceinline__ F3 qrot(float4 q, F3 x){
  F3 v = mk3(q.x, q.y, q.z);
  F3 t = cross3(v, x);
  t = mk3(2.f*t.x, 2.f*t.y, 2.f*t.z);
  F3 ct = cross3(v, t);
  return mk3(x.x + q.w*t.x + ct.x, x.y + q.w*t.y + ct.y, x.z + q.w*t.z + ct.z);
}
__device__ __forceinline__ float4 shflup4(float4 v, int d){
  return make_float4(__shfl_up(v.x,d,64), __shfl_up(v.y,d,64),
                     __shfl_up(v.z,d,64), __shfl_up(v.w,d,64));
}
__device__ __forceinline__ F3 shflF3(F3 v, int sl){
  return mk3(__shfl(v.x,sl,64), __shfl(v.y,sl,64), __shfl(v.z,sl,64));
}

extern "C" __global__ void __launch_bounds__(256)
rod_energy_wave(const float* __restrict__ verts,      // B,V,3
                const float* __restrict__ initd,      // B,3
                const float* __restrict__ restEdgeL,  // B,E
                const float* __restrict__ restRegionL,// B,E
                const float* __restrict__ Wprev,      // B,E,2
                const float* __restrict__ Wnext,      // B,E,2
                const float* __restrict__ theta,      // B,E
                const float* __restrict__ bend,       // (1|B),E
                const float* __restrict__ twist,      // (1|B),E
                float* __restrict__ out_m1,
                float* __restrict__ out_m2,
                float* __restrict__ out_kb,
                float* __restrict__ out_en,
                int V, int E, long long B, long long bendStride, long long twistStride)
{
  const int lane = threadIdx.x & 63;
  const int wv   = threadIdx.x >> 6;
  const long long r = (long long)blockIdx.x * 4 + wv;   // rod (wave-uniform)
  if (r >= B) return;

  const int e0i = 2*lane, e1i = 2*lane + 1;
  const bool a0 = e0i < E, a1 = e1i < E;
  const bool vg = (e0i + 1) < V;                        // vertices 2l,2l+1 exist
  const size_t rowE = (size_t)r * E;

  // ---- vertices 2l, 2l+1 : 3 x 8B-aligned float2 per lane (24B/lane contiguous) ----
  const float* vb = verts + (size_t)r * V * 3;
  float2 f01 = vg ? *(const float2*)(vb + e0i*3    ) : make_float2(0.f,0.f);
  float2 f23 = vg ? *(const float2*)(vb + e0i*3 + 2) : make_float2(0.f,0.f);
  float2 f45 = vg ? *(const float2*)(vb + e0i*3 + 4) : make_float2(0.f,0.f);
  F3 vA = mk3(f01.x, f01.y, f23.x);                     // v[2l]
  F3 vB = mk3(f23.y, f45.x, f45.y);                     // v[2l+1]
  F3 vC = mk3(__shfl_down(vA.x,1,64), __shfl_down(vA.y,1,64), __shfl_down(vA.z,1,64)); // v[2l+2]

  F3 E0 = mk3(vB.x-vA.x, vB.y-vA.y, vB.z-vA.z);         // edge 2l
  F3 E1 = mk3(vC.x-vB.x, vC.y-vB.y, vC.z-vB.z);         // edge 2l+1
  F3 Ep = mk3(__shfl_up(E1.x,1,64), __shfl_up(E1.y,1,64), __shfl_up(E1.z,1,64)); // edge 2l-1

  float rl0 = a0 ? restEdgeL[rowE+e0i] : 0.f;
  float rl1 = a1 ? restEdgeL[rowE+e1i] : 0.f;
  float rlp = __shfl_up(rl1,1,64);                      // restEdgeL[2l-1]

  // ---- per-edge kb + rotation quaternion + j flag ----
  // kb divides and cosP stay reference-exact (cond-sensitive); q via identity
  // sinP*axis = kb/sqrt(mag+4), cosP = 2/sqrt(mag+4).
  F3 kb0 = mk3(0.f,0.f,0.f), kb1 = mk3(0.f,0.f,0.f);
  float4 q0 = make_float4(0.f,0.f,0.f,1.f), q1 = q0;
  int j0 = 0, j1 = 0;
  if (a0 && e0i >= 1) {
    F3 cr = cross3(Ep, E0);
    float den = rlp*rl0 + dot3(Ep, E0);
    kb0 = mk3(2.f*cr.x/den, 2.f*cr.y/den, 2.f*cr.z/den);
    float mag = dot3(kb0, kb0);
    float cosP = sqrtf(4.f/(mag+4.f));
    if (!((1.f - cosP) <= ERRV)) {
      float rq = __builtin_amdgcn_rsqf(mag + 4.f);
      q0 = make_float4(kb0.x*rq, kb0.y*rq, kb0.z*rq, 2.f*rq);
      j0 = e0i;
    }
  }
  if (a1) {
    F3 cr = cross3(E0, E1);
    float den = rl0*rl1 + dot3(E0, E1);
    kb1 = mk3(2.f*cr.x/den, 2.f*cr.y/den, 2.f*cr.z/den);
    float mag = dot3(kb1, kb1);
    float cosP = sqrtf(4.f/(mag+4.f));
    if (!((1.f - cosP) <= ERRV)) {
      float rq = __builtin_amdgcn_rsqf(mag + 4.f);
      q1 = make_float4(kb1.x*rq, kb1.y*rq, kb1.z*rq, 2.f*rq);
      j1 = e1i;
    }
  }

  // ---- pairwise product + 6-step shuffle scan (no LDS, no barriers) ----
  float4 S = qmul(q1, q0);            // P_l = R_{2l+1} (x) R_{2l}
  int J = j0 > j1 ? j0 : j1;
  #pragma unroll
  for (int d = 1; d < 64; d <<= 1) {
    float4 t = shflup4(S, d);
    int tj = __shfl_up(J, d, 64);
    if (lane >= d) { S = qmul(S, t); J = J > tj ? J : tj; }
  }
  float4 Sp = shflup4(S, 1);
  int Jp = __shfl_up(J, 1, 64);
  if (lane == 0) { Sp = make_float4(0.f,0.f,0.f,1.f); Jp = 0; }
  const float4 M0 = qmul(q0, Sp);     // prefix through edge 2l
  const float4 M1 = S;                // prefix through edge 2l+1
  const int jm0 = j0 > Jp ? j0 : Jp;
  const int jm1 = J;

  // ---- u0, v0 (broadcast lane0's first edge) ----
  F3 e0b = shflF3(E0, 0);
  F3 dir = mk3(initd[r*3+0], initd[r*3+1], initd[r*3+2]);
  F3 n0  = cross3(e0b, dir);
  F3 u0g = norm3f(cross3(n0, e0b));
  F3 v0g = norm3f(cross3(e0b, u0g));

  // ---- u, v per edge (EDGE(j) via unconditional bpermute, select after) ----
  F3 u_0 = qrot(M0, u0g);             // identity prefix -> u0g bitwise
  F3 u_1 = qrot(M1, u0g);
  int sl0 = jm0 >> 1, sl1 = jm1 >> 1;
  F3 ea0 = shflF3(E0, sl0), eb0 = shflF3(E1, sl0);
  F3 ea1 = shflF3(E0, sl1), eb1 = shflF3(E1, sl1);
  F3 ej0 = (jm0 & 1) ? eb0 : ea0;
  F3 ej1 = (jm1 & 1) ? eb1 : ea1;
  F3 v_0 = (jm0 > 0) ? norm3f(cross3(ej0, u_0)) : v0g;
  F3 v_1 = (jm1 > 0) ? norm3f(cross3(ej1, u_1)) : v0g;

  // ---- material frame ----
  float th0 = a0 ? theta[rowE+e0i] : 0.f;
  float th1 = a1 ? theta[rowE+e1i] : 0.f;
  float thp = __shfl_up(th1, 1, 64);  // theta[2l-1]
  float s0,c0,s1,c1;
  __sincosf(th0, &s0, &c0);
  __sincosf(th1, &s1, &c1);
  F3 m1_0 = mk3(c0*u_0.x + s0*v_0.x, c0*u_0.y + s0*v_0.y, c0*u_0.z + s0*v_0.z);
  F3 m2_0 = mk3(-s0*m1_0.x + c0*v_0.x, -s0*m1_0.y + c0*v_0.y, -s0*m1_0.z + c0*v_0.z);
  F3 m1_1 = mk3(c1*u_1.x + s1*v_1.x, c1*u_1.y + s1*v_1.y, c1*u_1.z + s1*v_1.z);
  F3 m2_1 = mk3(-s1*m1_1.x + c1*v_1.x, -s1*m1_1.y + c1*v_1.y, -s1*m1_1.z + c1*v_1.z);

  // ---- stores (scalar, contiguous 24B/lane per array) ----
  const size_t o3 = (rowE + e0i) * 3;
  if (a0) {
    out_m1[o3+0]=m1_0.x; out_m1[o3+1]=m1_0.y; out_m1[o3+2]=m1_0.z;
    out_m2[o3+0]=m2_0.x; out_m2[o3+1]=m2_0.y; out_m2[o3+2]=m2_0.z;
    out_kb[o3+0]=kb0.x;  out_kb[o3+1]=kb0.y;  out_kb[o3+2]=kb0.z;
  }
  if (a1) {
    out_m1[o3+3]=m1_1.x; out_m1[o3+4]=m1_1.y; out_m1[o3+5]=m1_1.z;
    out_m2[o3+3]=m2_1.x; out_m2[o3+4]=m2_1.y; out_m2[o3+5]=m2_1.z;
    out_kb[o3+3]=kb1.x;  out_kb[o3+4]=kb1.y;  out_kb[o3+5]=kb1.z;
  }

  // ---- energy ----
  const float bsl = fmaxf(bend[bendStride*r + (E-1)], THRV);
  float contrib = 0.f;
  if (a0 && e0i >= 1) {
    float rrli = __builtin_amdgcn_rcpf(restRegionL[rowE+e0i]);
    float wx =  dot3(kb0, m2_0);
    float wy = -dot3(kb0, m1_0);
    float2 wp = *(const float2*)(Wprev + 2*(rowE+e0i));
    float2 wn = *(const float2*)(Wnext + 2*(rowE+e0i));
    float dpx = wx-wp.x, dpy = wy-wp.y, dnx = wx-wn.x, dny = wy-wn.y;
    float bsn = fmaxf(bend[bendStride*r + e0i], THRV);
    float dm  = th0 - thp;
    float ts  = fmaxf(twist[twistStride*r + e0i], THRV);
    contrib += (0.5f*(bsl*(dpx*dpx+dpy*dpy) + bsn*(dnx*dnx+dny*dny)) + 0.5f*ts*dm*dm) * rrli;
  }
  if (a1) {
    float rrli = __builtin_amdgcn_rcpf(restRegionL[rowE+e1i]);
    float wx =  dot3(kb1, m2_1);
    float wy = -dot3(kb1, m1_1);
    float2 wp = *(const float2*)(Wprev + 2*(rowE+e1i));
    float2 wn = *(const float2*)(Wnext + 2*(rowE+e1i));
    float dpx = wx-wp.x, dpy = wy-wp.y, dnx = wx-wn.x, dny = wy-wn.y;
    float bsn = fmaxf(bend[bendStride*r + e1i], THRV);
    float dm  = th1 - th0;
    float ts  = fmaxf(twist[twistStride*r + e1i], THRV);
    contrib += (0.5f*(bsl*(dpx*dpx+dpy*dpy) + bsn*(dnx*dnx+dny*dny)) + 0.5f*ts*dm*dm) * rrli;
  }
  #pragma unroll
  for (int m = 1; m < 64; m <<= 1) contrib += __shfl_xor(contrib, m, 64);
  if (lane == 0) out_en[r] = contrib;
}

extern "C" void kernel_launch(void* const* d_in, const int* in_sizes, int n_in,
                              void* d_out, int out_size, void* d_ws, size_t ws_size,
                              hipStream_t stream)
{
  const float* verts       = (const float*)d_in[0];
  const float* initd       = (const float*)d_in[1];
  const float* restEdgeL   = (const float*)d_in[2];
  const float* restRegionL = (const float*)d_in[3];
  const float* Wprev       = (const float*)d_in[4];
  const float* Wnext       = (const float*)d_in[5];
  const float* theta       = (const float*)d_in[6];
  const float* bend        = (const float*)d_in[7];
  const float* twist       = (const float*)d_in[8];

  long long B = in_sizes[1] / 3;
  long long V = (long long)in_sizes[0] / (3*B);
  long long E = V - 1;
  long long bendStride  = ((long long)in_sizes[7] >= B*E) ? E : 0;
  long long twistStride = ((long long)in_sizes[8] >= B*E) ? E : 0;

  float* out_m1 = (float*)d_out;
  float* out_m2 = out_m1 + (size_t)(B*E*3);
  float* out_kb = out_m2 + (size_t)(B*E*3);
  float* out_en = out_kb + (size_t)(B*E*3);

  dim3 grid((unsigned)((B + 3) / 4)), block(256);
  hipLaunchKernelGGL(rod_energy_wave, grid, block, 0, stream,
                     verts, initd, restEdgeL, restRegionL, Wprev, Wnext, theta,
                     bend, twist, out_m1, out_m2, out_kb, out_en,
                     (int)V, (int)E, B, bendStride, twistStride);
}

// Round 10
// 291.092 us; speedup vs baseline: 1.0365x; 1.0047x over previous
//
#include <hip/hip_runtime.h>

#define ERRV 1e-6f
#define THRV 1e-10f
#define MAXV 128

struct F3 { float x, y, z; };

__device__ __forceinline__ F3 mk3(float x, float y, float z){ F3 r; r.x=x; r.y=y; r.z=z; return r; }
__device__ __forceinline__ F3 cross3(F3 a, F3 b){
  return mk3(a.y*b.z - a.z*b.y, a.z*b.x - a.x*b.z, a.x*b.y - a.y*b.x);
}
__device__ __forceinline__ float dot3(F3 a, F3 b){ return a.x*b.x + a.y*b.y + a.z*b.z; }
__device__ __forceinline__ F3 norm3f(F3 a){
  float r = __builtin_amdgcn_rsqf(fmaxf(dot3(a,a), 1e-24f));
  return mk3(a.x*r, a.y*r, a.z*r);
}
// Hamilton product r = a (x) b : apply b first, then a.
__device__ __forceinline__ float4 qmul(float4 a, float4 b){
  float4 r;
  r.w = a.w*b.w - (a.x*b.x + a.y*b.y + a.z*b.z);
  r.x = a.w*b.x + b.w*a.x + (a.y*b.z - a.z*b.y);
  r.y = a.w*b.y + b.w*a.y + (a.z*b.x - a.x*b.z);
  r.z = a.w*b.z + b.w*a.z + (a.x*b.y - a.y*b.x);
  return r;
}
__device__ __forceinline__ F3 qrot(float4 q, F3 x){
  F3 v = mk3(q.x, q.y, q.z);
  F3 t = cross3(v, x);
  t = mk3(2.f*t.x, 2.f*t.y, 2.f*t.z);
  F3 ct = cross3(v, t);
  return mk3(x.x + q.w*t.x + ct.x, x.y + q.w*t.y + ct.y, x.z + q.w*t.z + ct.z);
}
__device__ __forceinline__ float4 shflup4(float4 v, int d){
  return make_float4(__shfl_up(v.x,d,64), __shfl_up(v.y,d,64),
                     __shfl_up(v.z,d,64), __shfl_up(v.w,d,64));
}

extern "C" __global__ void __launch_bounds__(MAXV)
rod_energy_kernel(const float* __restrict__ verts,      // B,V,3
                  const float* __restrict__ initd,      // B,3
                  const float* __restrict__ restEdgeL,  // B,E
                  const float* __restrict__ restRegionL,// B,E
                  const float* __restrict__ Wprev,      // B,E,2
                  const float* __restrict__ Wnext,      // B,E,2
                  const float* __restrict__ theta,      // B,E
                  const float* __restrict__ bend,       // (1|B),E
                  const float* __restrict__ twist,      // (1|B),E
                  float* __restrict__ out_m1,
                  float* __restrict__ out_m2,
                  float* __restrict__ out_kb,
                  float* __restrict__ out_en,
                  int V, int E, long long bendStride, long long twistStride)
{
  __shared__ float  sV[MAXV*3];   // raw vertex row
  __shared__ float4 sS;           // wave-0 scan total (quaternion)
  __shared__ int    sJt;          // wave-0 scan total (jmax)
  __shared__ float  sW[2];

  const int b    = blockIdx.x;
  const int e    = threadIdx.x;          // edge index
  const int lane = e & 63;
  const int wv   = e >> 6;
  const bool act = (e < E);

  // ---- stage vertex row into LDS with coalesced float4 loads ----
  const float* vb = verts + (size_t)b * V * 3;
  {
    const int nv4 = (V * 3) >> 2;
    if (e < nv4) ((float4*)sV)[e] = ((const float4*)vb)[e];
  }
  __syncthreads();

  #define EDGE(i) mk3(sV[((i)+1)*3+0]-sV[(i)*3+0], \
                      sV[((i)+1)*3+1]-sV[(i)*3+1], \
                      sV[((i)+1)*3+2]-sV[(i)*3+2])

  F3 edge = act ? EDGE(e) : mk3(0.f,0.f,0.f);

  // ---- kb + per-edge rotation quaternion ----
  // kb divides and cosP stay reference-exact (cond-sensitive); q via identity
  // sinP*axis = kb/sqrt(mag+4), cosP = 2/sqrt(mag+4).
  const size_t rowE = (size_t)b * E;
  F3 kb = mk3(0.f, 0.f, 0.f);
  float4 q = make_float4(0.f, 0.f, 0.f, 1.f);  // identity
  int j = 0;                                   // last edge index with a real rotation
  if (act && e >= 1) {
    F3 ep = EDGE(e-1);
    float rl  = restEdgeL[rowE + e];
    float rlp = restEdgeL[rowE + e - 1];
    F3 cr = cross3(ep, edge);
    float den = rlp*rl + dot3(ep, edge);
    kb = mk3(2.f*cr.x/den, 2.f*cr.y/den, 2.f*cr.z/den);   // exact divs (cond-sensitive)
    float mag  = dot3(kb, kb);
    float cosP = sqrtf(4.f/(mag+4.f));                    // exact (cond-sensitive)
    bool cond = (1.f - cosP) <= ERRV;                     // tiny rotation -> identity
    if (!cond) {
      float r = __builtin_amdgcn_rsqf(mag + 4.f);
      q = make_float4(kb.x*r, kb.y*r, kb.z*r, 2.f*r);     // unit by construction
      j = e;
    }
  }

  // ---- intra-wave inclusive shuffle scan (6 steps, no barriers) ----
  float4 S = q; int J = j;
  #pragma unroll
  for (int d = 1; d < 64; d <<= 1) {
    float4 t = shflup4(S, d);
    int tj = __shfl_up(J, d, 64);
    if (lane >= d) { S = qmul(S, t); J = J > tj ? J : tj; }
  }
  // ---- single inter-wave handoff: wave-1 composes with wave-0's total ----
  if (e == 63) { sS = S; sJt = J; }
  __syncthreads();
  if (wv == 1) {
    S = qmul(S, sS);
    J = J > sJt ? J : sJt;
  }
  q = S; j = J;                          // inclusive prefix across the block

  // ---- u0, v0 (all threads redundantly; wave-uniform) ----
  F3 e0  = EDGE(0);
  F3 dir = mk3(initd[(size_t)b*3+0], initd[(size_t)b*3+1], initd[(size_t)b*3+2]);
  F3 n0  = cross3(e0, dir);
  F3 u0  = norm3f(cross3(n0, e0));
  F3 v0  = norm3f(cross3(e0, u0));

  F3 u = u0, v = v0;
  if (act && e >= 1) {
    u = qrot(q, u0);                 // == u0 bitwise if prefix is all-identity
    if (j > 0) {
      F3 ej = EDGE(j);
      v = norm3f(cross3(ej, u));     // u unchanged since step j => matches reference rv
    }
  }

  // ---- material frame (hw sin/cos; |theta| small, err ~2^-21) ----
  float th = act ? theta[rowE + e] : 0.f;
  float cq, sq;
  __sincosf(th, &sq, &cq);
  F3 m1 = mk3(cq*u.x + sq*v.x, cq*u.y + sq*v.y, cq*u.z + sq*v.z);
  F3 m2 = mk3(-sq*m1.x + cq*v.x, -sq*m1.y + cq*v.y, -sq*m1.z + cq*v.z);

  // ---- outputs + energy contribution ----
  float contrib = 0.f;
  if (act) {
    size_t o3 = (rowE + e) * 3;
    out_m1[o3+0] = m1.x; out_m1[o3+1] = m1.y; out_m1[o3+2] = m1.z;
    out_m2[o3+0] = m2.x; out_m2[o3+1] = m2.y; out_m2[o3+2] = m2.z;
    out_kb[o3+0] = kb.x; out_kb[o3+1] = kb.y; out_kb[o3+2] = kb.z;
    if (e >= 1) {
      float rrli = __builtin_amdgcn_rcpf(restRegionL[rowE + e]);  // energy: abs-tiny, rcp ok
      float wx =  dot3(kb, m2);
      float wy = -dot3(kb, m1);
      float2 wp = ((const float2*)Wprev)[rowE + e];
      float2 wn = ((const float2*)Wnext)[rowE + e];
      float dpx = wx - wp.x, dpy = wy - wp.y;
      float dnx = wx - wn.x, dny = wy - wn.y;
      float bsl = fmaxf(bend[bendStride*b + (E-1)], THRV);
      float bsn = fmaxf(bend[bendStride*b + e],     THRV);
      contrib = 0.5f*(bsl*(dpx*dpx + dpy*dpy) + bsn*(dnx*dnx + dny*dny)) * rrli;
      float dm = th - theta[rowE + e - 1];
      float ts = fmaxf(twist[twistStride*b + e], THRV);
      contrib += 0.5f*ts*dm*dm * rrli;
    }
  }

  // ---- energy reduction: wave shuffle-reduce, then combine 2 waves ----
  float c = contrib;
  #pragma unroll
  for (int m = 1; m < 64; m <<= 1) c += __shfl_xor(c, m, 64);
  if (lane == 0) sW[wv] = c;
  __syncthreads();
  if (e == 0) out_en[b] = sW[0] + sW[1];
  #undef EDGE
}

extern "C" void kernel_launch(void* const* d_in, const int* in_sizes, int n_in,
                              void* d_out, int out_size, void* d_ws, size_t ws_size,
                              hipStream_t stream)
{
  const float* verts       = (const float*)d_in[0];
  const float* initd       = (const float*)d_in[1];
  const float* restEdgeL   = (const float*)d_in[2];
  const float* restRegionL = (const float*)d_in[3];
  const float* Wprev       = (const float*)d_in[4];
  const float* Wnext       = (const float*)d_in[5];
  const float* theta       = (const float*)d_in[6];
  const float* bend        = (const float*)d_in[7];
  const float* twist       = (const float*)d_in[8];

  long long B = in_sizes[1] / 3;
  long long V = (long long)in_sizes[0] / (3*B);
  long long E = V - 1;
  long long bendStride  = ((long long)in_sizes[7] >= B*E) ? E : 0;
  long long twistStride = ((long long)in_sizes[8] >= B*E) ? E : 0;

  float* out_m1 = (float*)d_out;
  float* out_m2 = out_m1 + (size_t)(B*E*3);
  float* out_kb = out_m2 + (size_t)(B*E*3);
  float* out_en = out_kb + (size_t)(B*E*3);

  dim3 grid((unsigned)B), block((unsigned)V);
  hipLaunchKernelGGL(rod_energy_kernel, grid, block, 0, stream,
                     verts, initd, restEdgeL, restRegionL, Wprev, Wnext, theta,
                     bend, twist, out_m1, out_m2, out_kb, out_en,
                     (int)V, (int)E, bendStride, twistStride);
}